// Round 1
// 407.759 us; speedup vs baseline: 1.8696x; 1.8696x over previous
//
#include <hip/hip_runtime.h>
#include <math.h>

// R5: replace the f32-VALU dot-product machine (MfmaUtil=0, 109 µs VALU floor)
// with bf16x3 split-precision MFMA GEMM. logits = x@W^T + b via
//   x = xh + xl (bf16 RNE), W = Wh + Wl;  acc += xh*Wh + xh*Wl + xl*Wh  (f32 MFMA acc)
// Residual ~2^-18 -> logit RMS err ~7e-6 (same order as f32 reorder noise).
// One fused kernel: GEMM + softmax + top-2 + renorm (finalize kernel removed).
// Workspace: 2 MB (Wh, Wl in fragment-linear order), prepared by prep_w.

#define T_TOKENS 16384
#define D_K      4096
#define N_EXP    128
#define TOK_BLK  64
#define KSTEP    64
#define NITER    (D_K / KSTEP)     // 64

typedef float  f32x4  __attribute__((ext_vector_type(4)));
typedef short  bf16x8 __attribute__((ext_vector_type(8)));
typedef float  fragc  __attribute__((ext_vector_type(4)));

__device__ __forceinline__ unsigned short bf16_rne(float f) {
    unsigned u = __float_as_uint(f);
    u += 0x7FFFu + ((u >> 16) & 1u);          // round-to-nearest-even
    return (unsigned short)(u >> 16);
}
__device__ __forceinline__ float bf16f(unsigned short h) {
    return __uint_as_float(((unsigned)h) << 16);
}

// A-fragment LDS offset with XOR swizzle: line L = G*64 + l holds 8 bf16 (16 B).
// swz = ((L>>3) ^ G) & 7 spreads the 8-k-group / kb / mtile bits across bank
// quads so both frag ds_read_b128 (lanes 0..63, fixed G) and staging
// ds_write_b128 are (near) conflict-free.
__device__ __forceinline__ int a_off(int G, int l) {
    const int L  = G * 64 + l;
    const int sw = ((L >> 3) ^ G) & 7;
    return (L << 4) ^ (sw << 4);
}

// ---------------------------------------------------------------------------
// prep_w: W [128][4096] f32 -> fragment-linear Wh, Wl bf16.
// Line index = (kbG*8 + nt)*64 + lane; lane holds W[nt*16+(l&15)][kbG*32+(l>>4)*8+j]
// (= B-fragment for mfma_f32_16x16x32_bf16: col=l&15, k=(l>>4)*8+j).
__global__ __launch_bounds__(256)
void prep_w(const float* __restrict__ W,
            short* __restrict__ wh, short* __restrict__ wl) {
    const int gid = blockIdx.x * 256 + threadIdx.x;   // 0..65535 lines
    const int l   = gid & 63;
    const int ntk = gid >> 6;                         // kbG*8 + nt
    const int e   = ((ntk & 7) << 4) + (l & 15);
    const int k   = ((ntk >> 3) << 5) + ((l >> 4) << 3);
    const float* src = W + (size_t)e * D_K + k;
    const f32x4 v0 = *(const f32x4*)src;
    const f32x4 v1 = *(const f32x4*)(src + 4);
    bf16x8 hv, lv;
#pragma unroll
    for (int j = 0; j < 8; ++j) {
        const float f = (j < 4) ? v0[j] : v1[j - 4];
        const unsigned short hh = bf16_rne(f);
        hv[j] = (short)hh;
        lv[j] = (short)bf16_rne(f - bf16f(hh));
    }
    *(bf16x8*)(wh + (size_t)gid * 8) = hv;
    *(bf16x8*)(wl + (size_t)gid * 8) = lv;
}

// ---------------------------------------------------------------------------
// Fused GEMM + softmax + top-2.
// 256 blocks x 256 thr (4 waves). Block: 64 tokens x 128 experts.
// Wave tile: 32 tok (2 Mtiles) x 64 exp (4 Ntiles) -> 8 acc tiles, 48 MFMA/iter.
// LDS: double-buffered x hi/lo frags (2 x 16 KB); epilogue aliases it.
#define LOGSTRIDE 140                       // 64x140 f32 logits, bank-spread
#define MERGE_OFF (64 * LOGSTRIDE * 4)      // 35840
#define SMEM_SZ   (MERGE_OFF + 64 * 4 * 8 * 4)   // 44032

__global__ __launch_bounds__(256, 1)
void router_mfma(const float* __restrict__ x,
                 const short* __restrict__ wh,
                 const short* __restrict__ wl,
                 const float* __restrict__ bvec,
                 float* __restrict__ out) {
    __shared__ __align__(16) char smem[SMEM_SZ];

    const int tid  = threadIdx.x;
    const int lane = tid & 63;
    const int w    = tid >> 6;
    const int wm   = w >> 1;          // token half
    const int wn   = w & 1;           // expert half
    const int g    = blockIdx.x;

    // staging role: thread covers (s_tok, 8 consecutive k); 2 rounds -> 64 tokens
    const int s_tok = tid >> 3;       // 0..31
    const int s_kc8 = tid & 7;        // 0..7
    const float* xsrc = x + (size_t)(g * TOK_BLK + s_tok) * D_K + s_kc8 * 8;
    const int kb_s = s_kc8 >> 2;
    const int l_s  = (s_tok & 15) | ((s_kc8 & 3) << 4);

    f32x4 ld[4];
    auto issue = [&](int t) {
        const float* p = xsrc + t * KSTEP;
        ld[0] = *(const f32x4*)p;
        ld[1] = *(const f32x4*)(p + 4);
        ld[2] = *(const f32x4*)(p + (size_t)32 * D_K);
        ld[3] = *(const f32x4*)(p + (size_t)32 * D_K + 4);
    };
    auto commit = [&](int bufbase) {
#pragma unroll
        for (int r = 0; r < 2; ++r) {
            const int tokL = s_tok + 32 * r;
            const int G    = kb_s * 4 + (tokL >> 4);
            const int off  = a_off(G, l_s);
            bf16x8 hv, lv;
#pragma unroll
            for (int j = 0; j < 8; ++j) {
                const float f = (j < 4) ? ld[2 * r][j] : ld[2 * r + 1][j - 4];
                const unsigned short hh = bf16_rne(f);
                hv[j] = (short)hh;
                lv[j] = (short)bf16_rne(f - bf16f(hh));
            }
            *(bf16x8*)(smem + bufbase + off)        = hv;
            *(bf16x8*)(smem + bufbase + 8192 + off) = lv;
        }
    };

    fragc acc[2][4];
#pragma unroll
    for (int mi = 0; mi < 2; ++mi)
#pragma unroll
        for (int nt = 0; nt < 4; ++nt)
            acc[mi][nt] = (fragc){0.f, 0.f, 0.f, 0.f};

    issue(0);
    commit(0);
    issue(1);
    __syncthreads();

    for (int t = 0; t < NITER; ++t) {
        const int cur = (t & 1) << 14;    // buffer byte offset (0 / 16384)
#pragma unroll
        for (int kb = 0; kb < 2; ++kb) {
            const int kbG = t * 2 + kb;
            bf16x8 bh[4], bl[4], ah[2], al[2];
#pragma unroll
            for (int nt = 0; nt < 4; ++nt) {
                const size_t line = ((size_t)(kbG * 8 + wn * 4 + nt)) * 64 + lane;
                bh[nt] = *(const bf16x8*)(wh + line * 8);   // coalesced, L2-hot
                bl[nt] = *(const bf16x8*)(wl + line * 8);
            }
#pragma unroll
            for (int mi = 0; mi < 2; ++mi) {
                const int G   = kb * 4 + wm * 2 + mi;
                const int off = a_off(G, lane);
                ah[mi] = *(const bf16x8*)(smem + cur + off);
                al[mi] = *(const bf16x8*)(smem + cur + 8192 + off);
            }
#pragma unroll
            for (int mi = 0; mi < 2; ++mi)
#pragma unroll
                for (int nt = 0; nt < 4; ++nt) {
                    acc[mi][nt] = __builtin_amdgcn_mfma_f32_16x16x32_bf16(
                        ah[mi], bh[nt], acc[mi][nt], 0, 0, 0);
                    acc[mi][nt] = __builtin_amdgcn_mfma_f32_16x16x32_bf16(
                        al[mi], bh[nt], acc[mi][nt], 0, 0, 0);
                    acc[mi][nt] = __builtin_amdgcn_mfma_f32_16x16x32_bf16(
                        ah[mi], bl[nt], acc[mi][nt], 0, 0, 0);
                }
        }
        if (t + 1 < NITER) {
            commit(16384 - cur);          // other buffer
            if (t + 2 < NITER) issue(t + 2);
        }
        __syncthreads();
    }

    // ---- epilogue: logits -> LDS, fused softmax + top-2 + renorm ----
    float* lg = (float*)smem;
#pragma unroll
    for (int mi = 0; mi < 2; ++mi) {
        const int row0 = (wm * 2 + mi) * 16 + ((lane >> 4) << 2);
#pragma unroll
        for (int nt = 0; nt < 4; ++nt) {
            const int col = wn * 64 + nt * 16 + (lane & 15);
#pragma unroll
            for (int j = 0; j < 4; ++j)
                lg[(row0 + j) * LOGSTRIDE + col] = acc[mi][nt][j];
        }
    }
    __syncthreads();

    // 4 threads per token scan 32 experts each (index-ascending, strict > :
    // first-occurrence tie-break, same as jax top_k)
    const int tok = tid & 63;
    const int q   = tid >> 6;             // wave-uniform
    const float* lrow = lg + tok * LOGSTRIDE + q * 32;
    const float* brow = bvec + q * 32;
    float v1 = -INFINITY, v2 = -INFINITY;
    int   i1 = 0, i2 = 0;
#pragma unroll 8
    for (int c = 0; c < 32; ++c) {
        const float lv = lrow[c] + brow[c];
        if (lv > v1)      { v2 = v1; i2 = i1; v1 = lv; i1 = c; }
        else if (lv > v2) { v2 = lv; i2 = c; }
    }
    float Z = 0.f;
#pragma unroll 8
    for (int c = 0; c < 32; ++c) Z += expf(lrow[c] + brow[c] - v1);

    float* mrow = (float*)(smem + MERGE_OFF) + (tok * 4 + q) * 8;
    mrow[0] = v1; mrow[1] = (float)(q * 32 + i1);
    mrow[2] = v2; mrow[3] = (float)(q * 32 + i2);
    mrow[4] = Z;
    __syncthreads();

    if (tid < 64) {
        const float* m0 = (float*)(smem + MERGE_OFF) + tid * 32;
        float V1 = m0[0], I1 = m0[1], V2 = m0[2], I2 = m0[3], Zs = m0[4];
#pragma unroll
        for (int q2 = 1; q2 < 4; ++q2) {
            const float* mq = m0 + q2 * 8;
            const float a1 = mq[0], ai1 = mq[1], a2 = mq[2], ai2 = mq[3], Zq = mq[4];
            const float M  = fmaxf(V1, a1);
            Zs = Zs * expf(V1 - M) + Zq * expf(a1 - M);
            if (a1 > V1)      { V2 = V1; I2 = I1; V1 = a1; I1 = ai1; }
            else if (a1 > V2) { V2 = a1; I2 = ai1; }
            if (a2 > V2)      { V2 = a2; I2 = ai2; }
        }
        const float p1 = 1.0f / Zs;               // exp(V1-V1)/Z
        const float p2 = expf(V2 - V1) / Zs;
        const float s  = p1 + p2 + 1e-8f;
        const int tokG = g * TOK_BLK + tid;
        float2* oidx  = (float2*)out;
        float2* oprob = ((float2*)out) + T_TOKENS;
        oidx[tokG]  = make_float2(I1, I2);
        oprob[tokG] = make_float2(p1 / s, p2 / s);
    }
}

extern "C" void kernel_launch(void* const* d_in, const int* in_sizes, int n_in,
                              void* d_out, int out_size, void* d_ws, size_t ws_size,
                              hipStream_t stream) {
    (void)in_sizes; (void)n_in; (void)out_size; (void)ws_size;
    const float* x = (const float*)d_in[0];
    const float* W = (const float*)d_in[1];
    const float* b = (const float*)d_in[2];
    float* out = (float*)d_out;
    short* wh = (short*)d_ws;                         // 1 MB
    short* wl = (short*)d_ws + (size_t)N_EXP * D_K;   // 1 MB

    prep_w<<<dim3(256), dim3(256), 0, stream>>>(W, wh, wl);
    router_mfma<<<dim3(T_TOKENS / TOK_BLK), dim3(256), 0, stream>>>(x, wh, wl, b, out);
}